// Round 1
// baseline (96.652 us; speedup 1.0000x reference)
//
#include <hip/hip_runtime.h>

// CMDNet (M=2, m={-1,+1}, equal alpha) — one wave (64 threads) handles 2 batches.
// lane = h*32 + k : h = batch-half within block, k = symbol index (0..31).
// Per lane: HH row k (32 f32 regs), state {G0,G1,ft0,ft1,xt}.
// Softmax over M=2 with equal alpha == sigmoid(tau*(G1-G0)) (shift-invariance, exact).
// grad_x * r = +/- 2*tau*ft0*ft1*r   (since 1-xt = 2*ft0, -1-xt = -2*ft1).

#define NRX 64
#define KSYM 32

__global__ __launch_bounds__(64, 4) void cmdnet_kernel(
    const float* __restrict__ yt,      // [B,64]
    const float* __restrict__ Ht,      // [B,64,32]
    const float* __restrict__ sigmat0, // [B]
    const float* __restrict__ taui,    // [niter+1]
    const float* __restrict__ delta,   // [niter]
    float* __restrict__ out_ft,        // [B,32,2]
    float* __restrict__ out_xt,        // [B,32]
    int niter)
{
    __shared__ __align__(16) float HtC[2][16][KSYM];  // 4 KB chunk (16 rows x 2 batches)
    __shared__ __align__(16) float ytL[2][NRX];
    __shared__ __align__(16) float xtL[2][KSYM];
    __shared__ float dL[64];
    __shared__ float tauL[64];

    const int lane = threadIdx.x;
    const int k = lane & 31;
    const int h = lane >> 5;
    const int bb = blockIdx.x * 2;
    const int b  = bb + h;

    // stage yt (both batches), delta, |taui[1..]|
    ytL[0][lane] = yt[(size_t)bb * NRX + lane];
    ytL[1][lane] = yt[(size_t)bb * NRX + NRX + lane];
    if (lane < niter) {
        dL[lane]   = delta[lane];
        tauL[lane] = fabsf(taui[lane + 1]);
    }

    float sig2 = sigmat0[b];
    sig2 *= sig2;

    float hh[KSYM];
    #pragma unroll
    for (int i = 0; i < KSYM; ++i) hh[i] = 0.f;
    float yh = 0.f;

    const float4* HtG = reinterpret_cast<const float4*>(Ht) + (size_t)bb * 512;

    // ---- HH = Ht^T Ht (row k per lane), yH, streamed in 16-row chunks ----
    for (int c = 0; c < 4; ++c) {
        __syncthreads();
        #pragma unroll
        for (int r = 0; r < 4; ++r) {
            int idx = r * 64 + lane;       // 0..255 float4s this chunk
            int bs  = idx >> 7;            // which batch
            int wi  = idx & 127;           // float4 within batch chunk
            float4 v = HtG[(size_t)bs * 512 + c * 128 + wi];
            reinterpret_cast<float4*>(&HtC[bs][0][0])[wi] = v;
        }
        __syncthreads();
        #pragma unroll
        for (int n = 0; n < 16; ++n) {
            float a = HtC[h][n][k];                      // per-lane column element
            yh = fmaf(ytL[h][c * 16 + n], a, yh);
            const float4* row = reinterpret_cast<const float4*>(&HtC[h][n][0]);
            #pragma unroll
            for (int t = 0; t < 8; ++t) {
                float4 rv = row[t];                      // broadcast read
                hh[t*4+0] = fmaf(a, rv.x, hh[t*4+0]);
                hh[t*4+1] = fmaf(a, rv.y, hh[t*4+1]);
                hh[t*4+2] = fmaf(a, rv.z, hh[t*4+2]);
                hh[t*4+3] = fmaf(a, rv.w, hh[t*4+3]);
            }
        }
    }

    // ---- initial state: G=0, tau=|taui[0]| -> softmax(0,0)=0.5, xt=0 (exact) ----
    float tau = fabsf(taui[0]);
    float G0 = 0.f, G1 = 0.f;
    float ft0 = 0.5f, ft1 = 0.5f, xt = 0.f;

    // ---- iterations ----
    for (int i = 0; i < niter; ++i) {
        __syncthreads();
        xtL[h][k] = xt;
        __syncthreads();

        float d        = dL[i];
        float tau_next = tauL[i];

        // xHH[k] = sum_l HH[k][l] * xt[l]   (HH symmetric)
        float acc = 0.f;
        const float4* xv = reinterpret_cast<const float4*>(&xtL[h][0]);
        #pragma unroll
        for (int t = 0; t < 8; ++t) {
            float4 x4 = xv[t];                           // broadcast read
            acc = fmaf(hh[t*4+0], x4.x, acc);
            acc = fmaf(hh[t*4+1], x4.y, acc);
            acc = fmaf(hh[t*4+2], x4.z, acc);
            acc = fmaf(hh[t*4+3], x4.w, acc);
        }
        float r = acc - yh;

        float p  = 2.f * tau * ft0 * ft1 * r;
        float e0 = __expf(-G0);
        float e1 = __expf(-G1);
        float g0 = fmaf(sig2, 1.f - e0, -p);
        float g1 = fmaf(sig2, 1.f - e1,  p);
        G0 = fmaf(-d, g0, G0);
        G1 = fmaf(-d, g1, G1);

        tau = tau_next;
        float z  = tau * (G1 - G0);
        float ez = __expf(-fabsf(z));
        float s  = __builtin_amdgcn_rcpf(1.f + ez);
        float abig = s, asml = ez * s;
        bool pos = (z >= 0.f);
        ft1 = pos ? abig : asml;
        ft0 = pos ? asml : abig;
        xt  = ft1 - ft0;
    }

    // ---- outputs ----
    float2 f2 = make_float2(ft0, ft1);
    reinterpret_cast<float2*>(out_ft)[(size_t)b * KSYM + k] = f2;
    out_xt[(size_t)b * KSYM + k] = xt;
}

extern "C" void kernel_launch(void* const* d_in, const int* in_sizes, int n_in,
                              void* d_out, int out_size, void* d_ws, size_t ws_size,
                              hipStream_t stream) {
    const float* yt    = (const float*)d_in[0];
    const float* Ht    = (const float*)d_in[1];
    const float* sg    = (const float*)d_in[2];
    const float* taui  = (const float*)d_in[3];
    const float* delta = (const float*)d_in[4];
    int B     = in_sizes[2];
    int niter = in_sizes[4];
    float* out    = (float*)d_out;
    float* out_ft = out;
    float* out_xt = out + (size_t)B * 64;

    dim3 grid(B / 2), block(64);
    hipLaunchKernelGGL(cmdnet_kernel, grid, block, 0, stream,
                       yt, Ht, sg, taui, delta, out_ft, out_xt, niter);
}